// Round 1
// baseline (104.944 us; speedup 1.0000x reference)
//
#include <hip/hip_runtime.h>
#include <math.h>

#define NCC 80
#define TOPKK 13
#define BB 16
#define NAA 8400
#define NMX 64
#define EPSF 1e-9f
#define IOUEPS 1e-7f
#define INV_PI2 0.4052847345693511f

__device__ __forceinline__ float ciou_pd(float gx1, float gy1, float gx2, float gy2,
                                         float gw, float gh, float gatan,
                                         float px1, float py1, float px2, float py2)
{
    float w2 = px2 - px1, h2 = py2 - py1;
    float iw = fmaxf(fminf(gx2, px2) - fmaxf(gx1, px1), 0.f);
    float ih = fmaxf(fminf(gy2, py2) - fmaxf(gy1, py1), 0.f);
    float inter = iw * ih;
    float uni = gw * gh + w2 * h2 - inter + IOUEPS;
    float iou = inter / uni;
    float cw = fmaxf(gx2, px2) - fminf(gx1, px1);
    float ch = fmaxf(gy2, py2) - fminf(gy1, py1);
    float c2 = cw * cw + ch * ch + IOUEPS;
    float dx = px1 + px2 - gx1 - gx2;
    float dy = py1 + py2 - gy1 - gy2;
    float rho2 = (dx * dx + dy * dy) / 4.f;
    float da = atanf(w2 / h2) - gatan;
    float v = INV_PI2 * da * da;
    float alpha = v / (v - iou + (1.f + IOUEPS));
    return iou - (rho2 / c2 + v * alpha);
}

// Kernel 1: one block per (b, j) row. Computes align_metric over all anchors,
// selects global top-13 (value desc, index asc — matches lax.top_k stability),
// then scatters count/jsum for candidates passing mask_in_gts.
__global__ __launch_bounds__(256) void k1_topk(
    const float* __restrict__ pd_scores,
    const float* __restrict__ pd_bboxes,
    const float* __restrict__ anc,
    const int*   __restrict__ gt_labels,
    const float* __restrict__ gt_bboxes,
    const float* __restrict__ mask_gt,
    int* __restrict__ cnt, int* __restrict__ jsum)
{
    const int row = blockIdx.x;
    const int b = row >> 6, j = row & 63;
    if (mask_gt[row] <= 0.f) return;  // row contributes nothing (count trick zeroes it)
    const int tid = threadIdx.x;
    const float4 g = reinterpret_cast<const float4*>(gt_bboxes)[row];
    const float gw = g.z - g.x, gh = g.w - g.y;
    const float gat = atanf(gw / gh);
    const int gl = gt_labels[row];
    const float* sc = pd_scores + (size_t)b * NAA * NCC + gl;
    const float4* pb = reinterpret_cast<const float4*>(pd_bboxes) + (size_t)b * NAA;
    const float2* ap2 = reinterpret_cast<const float2*>(anc);

    float lv[TOPKK]; int li[TOPKK];
#pragma unroll
    for (int k = 0; k < TOPKK; k++) { lv[k] = -1.f; li[k] = 0x7fffffff; }

    for (int a = tid; a < NAA; a += 256) {
        float2 ap = ap2[a];
        float din = fminf(fminf(ap.x - g.x, ap.y - g.y), fminf(g.z - ap.x, g.w - ap.y));
        float al = 0.f;
        if (din > EPSF) {
            float4 p = pb[a];
            float c = ciou_pd(g.x, g.y, g.z, g.w, gw, gh, gat, p.x, p.y, p.z, p.w);
            float o = fmaxf(c, 0.f);
            float o2 = o * o;
            al = sc[(size_t)a * NCC] * (o2 * o2 * o2);
        }
        // sorted insert, static indices only (bubble with early break)
        if (al > lv[TOPKK - 1]) {
            lv[TOPKK - 1] = al; li[TOPKK - 1] = a;
#pragma unroll
            for (int k = TOPKK - 1; k > 0; --k) {
                if (lv[k] > lv[k - 1]) {
                    float tv = lv[k]; lv[k] = lv[k - 1]; lv[k - 1] = tv;
                    int ti = li[k]; li[k] = li[k - 1]; li[k - 1] = ti;
                } else break;
            }
        }
    }

    // spill per-thread sorted lists to LDS (dynamic head index reads from LDS,
    // avoids scratch from runtime-indexed register arrays)
    __shared__ float Lv[256 * TOPKK];
    __shared__ int   Li[256 * TOPKK];
    __shared__ float sv[256];
    __shared__ int   si[256];
    __shared__ int   win[TOPKK];
#pragma unroll
    for (int k = 0; k < TOPKK; k++) { Lv[tid * TOPKK + k] = lv[k]; Li[tid * TOPKK + k] = li[k]; }
    __syncthreads();

    int p = 0;
    for (int r = 0; r < TOPKK; ++r) {
        sv[tid] = (p < TOPKK) ? Lv[tid * TOPKK + p] : -2.f;
        si[tid] = (p < TOPKK) ? Li[tid * TOPKK + p] : 0x7fffffff;
        __syncthreads();
        for (int s = 128; s > 0; s >>= 1) {
            if (tid < s) {
                float v2 = sv[tid + s]; int i2 = si[tid + s];
                if (v2 > sv[tid] || (v2 == sv[tid] && i2 < si[tid])) { sv[tid] = v2; si[tid] = i2; }
            }
            __syncthreads();
        }
        int wi = si[0];
        if (tid == 0) win[r] = wi;
        __syncthreads();
        if (p < TOPKK && Li[tid * TOPKK + p] == wi) ++p;
    }

    if (tid < TOPKK) {
        int a = win[tid];
        float2 ap = ap2[a];
        float din = fminf(fminf(ap.x - g.x, ap.y - g.y), fminf(g.z - ap.x, g.w - ap.y));
        if (din > EPSF) {  // mask_in_gts filter (mask_gt already >0)
            atomicAdd(&cnt[(size_t)b * NAA + a], 1);
            atomicAdd(&jsum[(size_t)b * NAA + a], j);
        }
    }
}

// Kernel 2: per-anchor multi-gt resolution + per-row pos_align/pos_ovl maxima.
__global__ __launch_bounds__(256) void k2_resolve(
    const float* __restrict__ pd_scores,
    const float* __restrict__ pd_bboxes,
    const float* __restrict__ anc,
    const int*   __restrict__ gt_labels,
    const float* __restrict__ gt_bboxes,
    const float* __restrict__ mask_gt,
    const int* __restrict__ cnt, const int* __restrict__ jsum,
    int* __restrict__ tgt, int* __restrict__ fgm, float* __restrict__ alv,
    unsigned int* __restrict__ pos_al, unsigned int* __restrict__ pos_ov)
{
    const size_t id = (size_t)blockIdx.x * 256 + threadIdx.x;
    if (id >= (size_t)BB * NAA) return;
    const int b = (int)(id / NAA);
    const int a = (int)(id % NAA);
    const int fg = cnt[id];
    float2 ap = reinterpret_cast<const float2*>(anc)[a];
    float4 p = reinterpret_cast<const float4*>(pd_bboxes)[id];
    int tj = 0, f = 0;
    if (fg == 1) { tj = jsum[id]; f = 1; }
    else if (fg > 1) {
        f = 1;
        float bv = -1.f; int bj = 0;
        for (int j = 0; j < NMX; ++j) {
            float4 g = reinterpret_cast<const float4*>(gt_bboxes)[b * NMX + j];
            float din = fminf(fminf(ap.x - g.x, ap.y - g.y), fminf(g.z - ap.x, g.w - ap.y));
            float ov = 0.f;
            if (din > EPSF && mask_gt[b * NMX + j] > 0.f) {
                float gw = g.z - g.x, gh = g.w - g.y;
                float c = ciou_pd(g.x, g.y, g.z, g.w, gw, gh, atanf(gw / gh), p.x, p.y, p.z, p.w);
                ov = fmaxf(c, 0.f);
            }
            if (ov > bv) { bv = ov; bj = j; }  // strict > keeps first max (jnp.argmax)
        }
        tj = bj;
    }
    float al = 0.f;
    if (f) {
        float4 g = reinterpret_cast<const float4*>(gt_bboxes)[b * NMX + tj];
        float din = fminf(fminf(ap.x - g.x, ap.y - g.y), fminf(g.z - ap.x, g.w - ap.y));
        if (din > EPSF && mask_gt[b * NMX + tj] > 0.f) {
            float gw = g.z - g.x, gh = g.w - g.y;
            float c = ciou_pd(g.x, g.y, g.z, g.w, gw, gh, atanf(gw / gh), p.x, p.y, p.z, p.w);
            float ov = fmaxf(c, 0.f);
            int gl = gt_labels[b * NMX + tj];
            float s = pd_scores[(size_t)(b * NAA + a) * NCC + gl];
            float o2 = ov * ov;
            al = s * (o2 * o2 * o2);
            atomicMax(&pos_ov[b * NMX + tj], __float_as_uint(ov));
        } else {
            atomicMax(&pos_ov[b * NMX + tj], 0u);
        }
        atomicMax(&pos_al[b * NMX + tj], __float_as_uint(al));
    }
    tgt[id] = tj; fgm[id] = f; alv[id] = al;
}

// Kernel 3: final outputs.
__global__ __launch_bounds__(256) void k3_out(
    const int* __restrict__ gt_labels,
    const float* __restrict__ gt_bboxes,
    const int* __restrict__ tgt, const int* __restrict__ fgm,
    const float* __restrict__ alv,
    const unsigned int* __restrict__ pos_al, const unsigned int* __restrict__ pos_ov,
    float* __restrict__ o_lab, float* __restrict__ o_box, float* __restrict__ o_sc,
    float* __restrict__ o_fg, float* __restrict__ o_ti)
{
    const size_t id = (size_t)blockIdx.x * 256 + threadIdx.x;
    if (id >= (size_t)BB * NAA) return;
    const int b = (int)(id / NAA);
    const int tj = tgt[id];
    const int f = fgm[id];
    int lab = gt_labels[b * NMX + tj]; lab = lab < 0 ? 0 : lab;
    float4 gb = reinterpret_cast<const float4*>(gt_bboxes)[b * NMX + tj];
    o_lab[id] = (float)lab;
    reinterpret_cast<float4*>(o_box)[id] = gb;
    o_fg[id] = f ? 1.f : 0.f;
    o_ti[id] = (float)tj;
    if (f) {
        float pa = __uint_as_float(pos_al[b * NMX + tj]);
        float po = __uint_as_float(pos_ov[b * NMX + tj]);
        o_sc[id * NCC + lab] = (alv[id] * po) / (pa + EPSF);
    }
}

extern "C" void kernel_launch(void* const* d_in, const int* in_sizes, int n_in,
                              void* d_out, int out_size, void* d_ws, size_t ws_size,
                              hipStream_t stream)
{
    const float* pd_scores = (const float*)d_in[0];
    const float* pd_bboxes = (const float*)d_in[1];
    const float* anc       = (const float*)d_in[2];
    // d_in[3] rfields: unused by the reference
    const int*   gt_labels = (const int*)d_in[4];
    const float* gt_bboxes = (const float*)d_in[5];
    const float* mask_gt   = (const float*)d_in[6];

    const size_t nba = (size_t)BB * NAA;
    int* cnt  = (int*)d_ws;
    int* jsum = cnt + nba;
    int* tgt  = jsum + nba;
    int* fgm  = tgt + nba;
    float* alv = (float*)(fgm + nba);
    unsigned int* pos_al = (unsigned int*)(alv + nba);
    unsigned int* pos_ov = pos_al + BB * NMX;

    float* out = (float*)d_out;
    float* o_lab = out;                 // (B,NA)
    float* o_box = out + nba;           // (B,NA,4)
    float* o_sc  = out + nba * 5;       // (B,NA,NC)
    float* o_fg  = out + nba * 85;      // (B,NA)
    float* o_ti  = out + nba * 86;      // (B,NA)

    hipMemsetAsync(d_out, 0, (size_t)out_size * sizeof(float), stream);
    hipMemsetAsync(cnt, 0, nba * 2 * sizeof(int), stream);
    hipMemsetAsync(pos_al, 0, (size_t)BB * NMX * 2 * sizeof(unsigned int), stream);

    k1_topk<<<BB * NMX, 256, 0, stream>>>(pd_scores, pd_bboxes, anc, gt_labels,
                                          gt_bboxes, mask_gt, cnt, jsum);
    const int nblk = (int)((nba + 255) / 256);
    k2_resolve<<<nblk, 256, 0, stream>>>(pd_scores, pd_bboxes, anc, gt_labels,
                                         gt_bboxes, mask_gt, cnt, jsum,
                                         tgt, fgm, alv, pos_al, pos_ov);
    k3_out<<<nblk, 256, 0, stream>>>(gt_labels, gt_bboxes, tgt, fgm, alv,
                                     pos_al, pos_ov, o_lab, o_box, o_sc, o_fg, o_ti);
}